// Round 2
// baseline (421.272 us; speedup 1.0000x reference)
//
#include <hip/hip_runtime.h>
#include <math.h>

// Problem constants (from reference): S=4, B=8, C=9, H=W=512
constexpr int  Sn = 4;
constexpr int  Bn = 8;
constexpr int  Cn = 9;
constexpr int  HWc = 512 * 512;                 // 2^18 pixels per (s,b,c) plane
constexpr long SSTRIDE = (long)Bn * Cn * HWc;   // element stride between stages

typedef float v4f __attribute__((ext_vector_type(4)));

__global__ __launch_bounds__(256) void weighted_fusion_kernel(
    const float* __restrict__ pred,   // [S,B,C,H,W]
    const float* __restrict__ wmat,   // [S,C]
    const float* __restrict__ bvec,   // [S]
    float* __restrict__ out)          // [B,C,H,W]
{
    int tid = blockIdx.x * 256 + threadIdx.x;
    long p4 = (long)tid * 4;                  // first pixel this thread owns (4 per thread)
    int b  = (int)(p4 >> 18);                 // / HW
    int hw = (int)(p4 & (HWc - 1));           // % HW
    long toff = (long)b * Cn * HWc + hw;      // shared thread offset for loads AND stores

    // Online (un-shifted) softmax-weighted accumulation.
    // w ~ 0.1*N(0,1)  =>  |wm| <~ 5, exp() needs no max-subtraction at fp32.
    v4f acc[Cn];
    #pragma unroll
    for (int c = 0; c < Cn; ++c) acc[c] = 0.0f;
    v4f l = 0.0f;

    #pragma unroll
    for (int s = 0; s < Sn; ++s) {
        // ---- stream this stage's 9 planes (16 B/lane, coalesced) ----
        // NOTE: plain (cached) loads this round — single-variable A/B vs round 1's
        // nontemporal loads, to discriminate "NT caps read BW" from
        // "dur_us is dominated by harness re-poison fills".
        v4f pr[Cn];
        #pragma unroll
        for (int c = 0; c < Cn; ++c) {
            const v4f* p = reinterpret_cast<const v4f*>(
                pred + (long)s * SSTRIDE + (long)c * HWc + toff);
            pr[c] = *p;
        }

        // ---- 1x1 conv: wm = b[s] + sum_c pr[c]*w[s][c] (w loads are uniform -> s_load) ----
        v4f a = bvec[s];
        #pragma unroll
        for (int c = 0; c < Cn; ++c) a += pr[c] * wmat[s * Cn + c];

        // ---- unnormalized softmax weight, accumulate fusion in place ----
        v4f e;
        e.x = __expf(a.x); e.y = __expf(a.y);
        e.z = __expf(a.z); e.w = __expf(a.w);
        l += e;
        #pragma unroll
        for (int c = 0; c < Cn; ++c) acc[c] += pr[c] * e;
    }

    // ---- normalize and store (stores stay NT: output is never re-read) ----
    v4f rl;
    rl.x = __builtin_amdgcn_rcpf(l.x);
    rl.y = __builtin_amdgcn_rcpf(l.y);
    rl.z = __builtin_amdgcn_rcpf(l.z);
    rl.w = __builtin_amdgcn_rcpf(l.w);

    float* obase = out + toff;
    #pragma unroll
    for (int c = 0; c < Cn; ++c) {
        __builtin_nontemporal_store(acc[c] * rl,
            reinterpret_cast<v4f*>(obase + (long)c * HWc));
    }
}

extern "C" void kernel_launch(void* const* d_in, const int* in_sizes, int n_in,
                              void* d_out, int out_size, void* d_ws, size_t ws_size,
                              hipStream_t stream) {
    const float* pred = (const float*)d_in[0];   // [S,B,C,H,W] fp32
    const float* w    = (const float*)d_in[1];   // [S,C] fp32
    const float* bias = (const float*)d_in[2];   // [S] fp32
    float* out        = (float*)d_out;           // [B,C,H,W] fp32

    const int total_threads = (Bn * HWc) / 4;    // 524288: one thread per 4 pixels
    const int block = 256;
    const int grid  = total_threads / block;     // 2048
    weighted_fusion_kernel<<<grid, block, 0, stream>>>(pred, w, bias, out);
}

// Round 3
// 393.950 us; speedup vs baseline: 1.0694x; 1.0694x over previous
//
#include <hip/hip_runtime.h>
#include <math.h>

// Problem constants (from reference): S=4, B=8, C=9, H=W=512
constexpr int  Sn = 4;
constexpr int  Bn = 8;
constexpr int  Cn = 9;
constexpr int  HWc = 512 * 512;                 // 2^18 pixels per (s,b,c) plane
constexpr long SSTRIDE = (long)Bn * Cn * HWc;   // element stride between stages

typedef float v4f __attribute__((ext_vector_type(4)));

__global__ __launch_bounds__(256) void weighted_fusion_kernel(
    const float* __restrict__ pred,   // [S,B,C,H,W]
    const float* __restrict__ wmat,   // [S,C]
    const float* __restrict__ bvec,   // [S]
    float* __restrict__ out)          // [B,C,H,W]
{
    int tid = blockIdx.x * 256 + threadIdx.x;
    long p4 = (long)tid * 4;                  // first pixel this thread owns (4 per thread)
    int b  = (int)(p4 >> 18);                 // / HW
    int hw = (int)(p4 & (HWc - 1));           // % HW
    long toff = (long)b * Cn * HWc + hw;      // shared thread offset for loads AND stores

    // Online (un-shifted) softmax-weighted accumulation.
    // w ~ 0.1*N(0,1)  =>  |wm| <~ 5, exp() needs no max-subtraction at fp32.
    v4f acc[Cn];
    #pragma unroll
    for (int c = 0; c < Cn; ++c) acc[c] = 0.0f;
    v4f l = 0.0f;

    #pragma unroll
    for (int s = 0; s < Sn; ++s) {
        // ---- stream this stage's 9 planes (16 B/lane, coalesced) ----
        // NT loads are a measured -26 us vs cached loads (round-2 A/B):
        // pure streaming data, nt bit avoids L2/L3 allocation churn.
        v4f pr[Cn];
        #pragma unroll
        for (int c = 0; c < Cn; ++c) {
            const v4f* p = reinterpret_cast<const v4f*>(
                pred + (long)s * SSTRIDE + (long)c * HWc + toff);
            pr[c] = __builtin_nontemporal_load(p);
        }

        // ---- 1x1 conv: wm = b[s] + sum_c pr[c]*w[s][c] (w loads are uniform -> s_load) ----
        v4f a = bvec[s];
        #pragma unroll
        for (int c = 0; c < Cn; ++c) a += pr[c] * wmat[s * Cn + c];

        // ---- unnormalized softmax weight, accumulate fusion in place ----
        v4f e;
        e.x = __expf(a.x); e.y = __expf(a.y);
        e.z = __expf(a.z); e.w = __expf(a.w);
        l += e;
        #pragma unroll
        for (int c = 0; c < Cn; ++c) acc[c] += pr[c] * e;
    }

    // ---- normalize and store (stores stay NT: output is never re-read) ----
    v4f rl;
    rl.x = __builtin_amdgcn_rcpf(l.x);
    rl.y = __builtin_amdgcn_rcpf(l.y);
    rl.z = __builtin_amdgcn_rcpf(l.z);
    rl.w = __builtin_amdgcn_rcpf(l.w);

    float* obase = out + toff;
    #pragma unroll
    for (int c = 0; c < Cn; ++c) {
        __builtin_nontemporal_store(acc[c] * rl,
            reinterpret_cast<v4f*>(obase + (long)c * HWc));
    }
}

extern "C" void kernel_launch(void* const* d_in, const int* in_sizes, int n_in,
                              void* d_out, int out_size, void* d_ws, size_t ws_size,
                              hipStream_t stream) {
    const float* pred = (const float*)d_in[0];   // [S,B,C,H,W] fp32
    const float* w    = (const float*)d_in[1];   // [S,C] fp32
    const float* bias = (const float*)d_in[2];   // [S] fp32
    float* out        = (float*)d_out;           // [B,C,H,W] fp32

    const int total_threads = (Bn * HWc) / 4;    // 524288: one thread per 4 pixels
    const int block = 256;
    const int grid  = total_threads / block;     // 2048
    weighted_fusion_kernel<<<grid, block, 0, stream>>>(pred, w, bias, out);
}